// Round 4
// baseline (344.323 us; speedup 1.0000x reference)
//
#include <hip/hip_runtime.h>

#define T_TOK 16384
#define H_DIM 4096
#define O_DIM 4096
#define NA 8
#define RANK 16
#define NCHUNK 32          // h-chunks of 128 cols
#define NPE 32             // tokens per expand block

typedef float f32x4 __attribute__((ext_vector_type(4)));

// ---------------- sort-by-adapter machinery ----------------

__global__ void k_zero(int* __restrict__ counts) {
    if (threadIdx.x < NA) counts[threadIdx.x] = 0;
}

__global__ void k_zerov(float* __restrict__ V) {
    ((f32x4*)V)[blockIdx.x * 256 + threadIdx.x] = (f32x4){0.f, 0.f, 0.f, 0.f};
}

__global__ void k_hist(const int* __restrict__ idx, int* __restrict__ counts) {
    __shared__ int h[NA];
    if (threadIdx.x < NA) h[threadIdx.x] = 0;
    __syncthreads();
    int t = blockIdx.x * blockDim.x + threadIdx.x;
    atomicAdd(&h[idx[t]], 1);
    __syncthreads();
    if (threadIdx.x < NA) atomicAdd(&counts[threadIdx.x], h[threadIdx.x]);
}

__global__ void k_prefix(const int* __restrict__ counts, int* __restrict__ offs,
                         int* __restrict__ cursor) {
    if (threadIdx.x == 0) {
        int run = 0;
        for (int n = 0; n < NA; n++) { offs[n] = run; cursor[n] = run; run += counts[n]; }
    }
}

__global__ void k_scatter(const int* __restrict__ idx, int* __restrict__ cursor,
                          int* __restrict__ order) {
    int t = blockIdx.x * blockDim.x + threadIdx.x;
    int a = idx[t];
    int lane = threadIdx.x & 63;
    for (int n = 0; n < NA; n++) {
        unsigned long long m = __ballot(a == n);
        if (m) {
            int leader = __ffsll((unsigned long long)m) - 1;
            int cnt = __popcll(m);
            int base = 0;
            if (lane == leader) base = atomicAdd(&cursor[n], cnt);
            base = __shfl(base, leader);
            if (a == n) {
                int rank = __popcll(m & ((1ull << lane) - 1ull));
                order[base + rank] = t;
            }
        }
    }
}

// ---------------- transpose A -> AT[n][r][h] ----------------

__global__ void k_transpose(const float* __restrict__ A, float* __restrict__ AT) {
    const int n = blockIdx.y;
    const int h0 = blockIdx.x * 256;
    __shared__ float lds[256 * RANK];
    const float4* src = (const float4*)(A + ((size_t)n * H_DIM + h0) * RANK);
#pragma unroll
    for (int k = 0; k < 4; ++k)
        ((float4*)lds)[k * 256 + threadIdx.x] = src[k * 256 + threadIdx.x];
    __syncthreads();
    float* dst = AT + (size_t)n * RANK * H_DIM;
#pragma unroll
    for (int k = 0; k < RANK; ++k)
        dst[(size_t)k * H_DIM + h0 + threadIdx.x] = lds[threadIdx.x * RANK + k];
}

// ---------------- shrink: partial dot per 128-col chunk ----------------
// grid (8, NBLK_Y, 8), block 256 = 4 waves; wave w covers chunk blockIdx.x*4+w.
// lane: r = lane&15, hg = lane>>4. Per lane: cols c0 + j*16 + hg*4, j=0..7 (span 128).
// at4[8] loop-invariant in registers. MODE 0: store P[chunk][t][16]; MODE 1: atomicAdd V.

template <int MODE>
__global__ __launch_bounds__(256, 2) void k_shrink(
    const float* __restrict__ x, const float* __restrict__ at,
    const int* __restrict__ order, const int* __restrict__ counts,
    const int* __restrict__ offs, float* __restrict__ P) {
    const int n = blockIdx.z;
    const int cnt = counts[n];
    if (cnt == 0) return;
    const int seg = offs[n];
    const int w = threadIdx.x >> 6, lane = threadIdx.x & 63;
    const int chunk = blockIdx.x * 4 + w;
    const int r = lane & 15, hg = lane >> 4;
    const int c0 = chunk * 128;
    const int nblk = gridDim.y;
    const int p0 = (int)(((long long)cnt * blockIdx.y) / nblk);
    const int p1 = (int)(((long long)cnt * (blockIdx.y + 1)) / nblk);
    if (p0 >= p1) return;

    const float* At = at + ((size_t)n * RANK + r) * H_DIM + c0 + hg * 4;
    f32x4 at4[8];
#pragma unroll
    for (int j = 0; j < 8; j++) at4[j] = *(const f32x4*)(At + j * 16);

    const float* xc = x + c0 + hg * 4;
    int tok = order[seg + p0];
    for (int p = p0; p < p1; ++p) {
        const int tok_next = (p + 1 < p1) ? order[seg + p + 1] : 0;
        const float* xr = xc + (size_t)tok * H_DIM;
        f32x4 xv[8];
#pragma unroll
        for (int j = 0; j < 8; j++) xv[j] = *(const f32x4*)(xr + j * 16);
        f32x4 a4 = {0.f, 0.f, 0.f, 0.f};
#pragma unroll
        for (int j = 0; j < 8; j++) {
            a4.x = fmaf(xv[j].x, at4[j].x, a4.x);
            a4.y = fmaf(xv[j].y, at4[j].y, a4.y);
            a4.z = fmaf(xv[j].z, at4[j].z, a4.z);
            a4.w = fmaf(xv[j].w, at4[j].w, a4.w);
        }
        float acc = (a4.x + a4.y) + (a4.z + a4.w);
        acc += __shfl_xor(acc, 16);
        acc += __shfl_xor(acc, 32);
        if (lane < 16) {
            if (MODE == 0)
                P[((size_t)chunk * T_TOK + (seg + p)) * RANK + r] = acc;
            else
                atomicAdd(&P[(size_t)(seg + p) * RANK + r], acc);
        }
        tok = tok_next;
    }
}

// ---------------- reduce P[32][T][16] -> V[T][16] ----------------

__global__ void k_reducev(const float* __restrict__ P, float* __restrict__ V) {
    const int i = blockIdx.x * 256 + threadIdx.x;      // f32x4 index, < T*4
    const f32x4* Pb = (const f32x4*)P;
    f32x4 s0 = {0.f, 0.f, 0.f, 0.f}, s1 = s0, s2 = s0, s3 = s0;
#pragma unroll
    for (int c = 0; c < NCHUNK; c += 4) {
        s0 += Pb[(size_t)(c + 0) * T_TOK * 4 + i];
        s1 += Pb[(size_t)(c + 1) * T_TOK * 4 + i];
        s2 += Pb[(size_t)(c + 2) * T_TOK * 4 + i];
        s3 += Pb[(size_t)(c + 3) * T_TOK * 4 + i];
    }
    ((f32x4*)V)[i] = (s0 + s1) + (s2 + s3);
}

// ---------------- expand: out[t] = result[t] + V[p] @ B[n] ----------------
// grid (4, 512, 8), block 256; B slice in regs (64 VGPR); 2-deep result prefetch; NT store.

__global__ __launch_bounds__(256, 2) void k_expand(
    const float* __restrict__ result, const float* __restrict__ lora_b,
    const float* __restrict__ V, const int* __restrict__ order,
    const int* __restrict__ counts, const int* __restrict__ offs,
    float* __restrict__ out) {
    const int n = blockIdx.z;
    const int cnt = counts[n];
    const int pbase = blockIdx.y * NPE;
    if (pbase >= cnt) return;
    const int seg = offs[n];
    const int o0 = blockIdx.x * 1024 + (threadIdx.x << 2);

    __shared__ float vlds[NPE * RANK];
    __shared__ int olds[NPE];
    const int np = min(NPE, cnt - pbase);

    if (threadIdx.x < np * 4)
        ((f32x4*)vlds)[threadIdx.x] =
            ((const f32x4*)V)[(size_t)(seg + pbase) * 4 + threadIdx.x];
    if (threadIdx.x < np) olds[threadIdx.x] = order[seg + pbase + threadIdx.x];

    f32x4 b[RANK];
    const float* Bn = lora_b + (size_t)n * RANK * O_DIM;
#pragma unroll
    for (int r = 0; r < RANK; r++)
        b[r] = *(const f32x4*)(Bn + (size_t)r * O_DIM + o0);

    __syncthreads();

    size_t offA = (size_t)olds[0] * O_DIM + o0;
    f32x4 rA = *(const f32x4*)(result + offA);
    size_t offB = 0;
    f32x4 rB = rA;
    if (np > 1) {
        offB = (size_t)olds[1] * O_DIM + o0;
        rB = *(const f32x4*)(result + offB);
    }

    for (int p = 0; p < np; ++p) {
        f32x4 rC = rB;
        size_t offC = 0;
        if (p + 2 < np) {
            offC = (size_t)olds[p + 2] * O_DIM + o0;
            rC = *(const f32x4*)(result + offC);
        }
        float va[RANK];
#pragma unroll
        for (int q = 0; q < 4; q++)
            *(f32x4*)&va[q * 4] = *(const f32x4*)&vlds[p * RANK + q * 4];
        f32x4 acc = rA;
#pragma unroll
        for (int r = 0; r < RANK; r++) {
            acc.x = fmaf(va[r], b[r].x, acc.x);
            acc.y = fmaf(va[r], b[r].y, acc.y);
            acc.z = fmaf(va[r], b[r].z, acc.z);
            acc.w = fmaf(va[r], b[r].w, acc.w);
        }
        __builtin_nontemporal_store(acc, (f32x4*)(out + offA));
        rA = rB; offA = offB;
        rB = rC; offB = offC;
    }
}

// ---------------- launch ----------------

extern "C" void kernel_launch(void* const* d_in, const int* in_sizes, int n_in,
                              void* d_out, int out_size, void* d_ws, size_t ws_size,
                              hipStream_t stream) {
    const float* result = (const float*)d_in[0];
    const float* x      = (const float*)d_in[1];
    const float* lora_a = (const float*)d_in[2];
    const float* lora_b = (const float*)d_in[3];
    const int*   aidx   = (const int*)d_in[4];
    float* out = (float*)d_out;

    const size_t vbytes  = (size_t)T_TOK * RANK * 4;             // 1 MB
    const size_t obytes  = (size_t)T_TOK * 4 + 3 * NA * 4;       // order + counters
    const size_t atbytes = (size_t)NA * RANK * H_DIM * 4;        // 2 MB
    const size_t pbytes  = (size_t)NCHUNK * T_TOK * RANK * 4;    // 32 MB
    const size_t base_need = vbytes + obytes + atbytes;          // ~3.07 MB
    const bool big = ws_size >= base_need + pbytes;

    float* V    = (float*)d_ws;
    int* order  = (int*)((char*)d_ws + vbytes);
    int* counts = order + T_TOK;
    int* offs   = counts + NA;
    int* cursor = offs + NA;
    float* AT   = (float*)(cursor + NA);
    float* P    = (float*)((char*)d_ws + base_need);             // big path only

    k_zero<<<dim3(1), dim3(64), 0, stream>>>(counts);
    k_hist<<<dim3(64), dim3(256), 0, stream>>>(aidx, counts);
    k_prefix<<<dim3(1), dim3(64), 0, stream>>>(counts, offs, cursor);
    k_scatter<<<dim3(64), dim3(256), 0, stream>>>(aidx, cursor, order);
    k_transpose<<<dim3(16, NA), dim3(256), 0, stream>>>(lora_a, AT);

    if (big) {
        k_shrink<0><<<dim3(8, 16, NA), dim3(256), 0, stream>>>(x, AT, order, counts, offs, P);
        k_reducev<<<dim3(T_TOK * 4 / 256), dim3(256), 0, stream>>>(P, V);
    } else {
        k_zerov<<<dim3(T_TOK * 4 / 256 / 4), dim3(256), 0, stream>>>(V);
        k_shrink<1><<<dim3(8, 16, NA), dim3(256), 0, stream>>>(x, AT, order, counts, offs, V);
    }
    k_expand<<<dim3(4, 512, NA), dim3(256), 0, stream>>>(result, lora_b, V, order, counts, offs, out);
}

// Round 5
// 265.102 us; speedup vs baseline: 1.2988x; 1.2988x over previous
//
#include <hip/hip_runtime.h>

#define T_TOK 16384
#define H_DIM 4096
#define O_DIM 4096
#define NA 8
#define RANK 16
#define NPIECE 32          // half-chunk partials (16 chunks x 2)
#define NPE 32             // tokens per expand block

typedef float f32x4 __attribute__((ext_vector_type(4)));

// v_add_f32 with DPP on src0: x = dpp(x) + x  (pure VALU cross-lane)
#define DPP_ADD(x, ctrl) \
    asm("v_add_f32 %0, %0, %0 " ctrl " row_mask:0xf bank_mask:0xf" : "+v"(x))

// ---------------- sort-by-adapter machinery ----------------

__global__ void k_zero(int* __restrict__ counts) {
    if (threadIdx.x < NA) counts[threadIdx.x] = 0;
}

__global__ void k_zerov(float* __restrict__ V) {
    ((f32x4*)V)[blockIdx.x * 256 + threadIdx.x] = (f32x4){0.f, 0.f, 0.f, 0.f};
}

__global__ void k_hist(const int* __restrict__ idx, int* __restrict__ counts) {
    __shared__ int h[NA];
    if (threadIdx.x < NA) h[threadIdx.x] = 0;
    __syncthreads();
    int t = blockIdx.x * blockDim.x + threadIdx.x;
    atomicAdd(&h[idx[t]], 1);
    __syncthreads();
    if (threadIdx.x < NA) atomicAdd(&counts[threadIdx.x], h[threadIdx.x]);
}

__global__ void k_prefix(const int* __restrict__ counts, int* __restrict__ offs,
                         int* __restrict__ cursor) {
    if (threadIdx.x == 0) {
        int run = 0;
        for (int n = 0; n < NA; n++) { offs[n] = run; cursor[n] = run; run += counts[n]; }
    }
}

__global__ void k_scatter(const int* __restrict__ idx, int* __restrict__ cursor,
                          int* __restrict__ order) {
    int t = blockIdx.x * blockDim.x + threadIdx.x;
    int a = idx[t];
    int lane = threadIdx.x & 63;
    for (int n = 0; n < NA; n++) {
        unsigned long long m = __ballot(a == n);
        if (m) {
            int leader = __ffsll((unsigned long long)m) - 1;
            int cnt = __popcll(m);
            int base = 0;
            if (lane == leader) base = atomicAdd(&cursor[n], cnt);
            base = __shfl(base, leader);
            if (a == n) {
                int rank = __popcll(m & ((1ull << lane) - 1ull));
                order[base + rank] = t;
            }
        }
    }
}

// ---------------- transpose A -> AT[n][r][h] ----------------

__global__ void k_transpose(const float* __restrict__ A, float* __restrict__ AT) {
    const int n = blockIdx.y;
    const int h0 = blockIdx.x * 256;
    __shared__ float lds[256 * RANK];
    const float4* src = (const float4*)(A + ((size_t)n * H_DIM + h0) * RANK);
#pragma unroll
    for (int k = 0; k < 4; ++k)
        ((float4*)lds)[k * 256 + threadIdx.x] = src[k * 256 + threadIdx.x];
    __syncthreads();
    float* dst = AT + (size_t)n * RANK * H_DIM;
#pragma unroll
    for (int k = 0; k < RANK; ++k)
        dst[(size_t)k * H_DIM + h0 + threadIdx.x] = lds[threadIdx.x * RANK + k];
}

// ---------------- shrink: col-in-lane, DPP reduce ----------------
// grid (4, 32, 8), block 256 = 4 waves; wave w owns chunk blockIdx.x*4+w (256 cols).
// lane holds cols c0+lane*4 (f32x4) -> one 1KB fully-coalesced load per token.
// at4[16] loop-invariant (64 VGPR). Reduce: quad xor1,xor2 + row_ror 4,8 (VALU DPP)
// + ds_swizzle xor16 -> two half-partials per chunk -> P[32][T][16].
// 2-group (8-token) software pipeline keeps 8KB/wave of loads in flight.

template <int MODE>   // 0: store P pieces; 1: full reduce + atomicAdd into V
__global__ __launch_bounds__(256, 3) void k_shrink(
    const float* __restrict__ x, const float* __restrict__ at,
    const int* __restrict__ order, const int* __restrict__ counts,
    const int* __restrict__ offs, float* __restrict__ P) {
    const int n = blockIdx.z;
    const int cnt = counts[n];
    if (cnt == 0) return;
    const int seg = offs[n];
    const int w = threadIdx.x >> 6, lane = threadIdx.x & 63;
    const int chunk = blockIdx.x * 4 + w;
    const int c0 = chunk * 256;
    const int rsel = lane & 15;
    const int piece = chunk * 2 + (lane >> 5);
    const int nblk = gridDim.y, by = blockIdx.y;
    int p0 = (int)(((long long)cnt * by) / nblk) & ~3;
    int p1 = (by == nblk - 1) ? cnt : ((int)(((long long)cnt * (by + 1)) / nblk) & ~3);
    if (p0 >= p1) return;

    const float* Atn = at + (size_t)n * RANK * H_DIM + c0 + lane * 4;
    f32x4 at4[16];
#pragma unroll
    for (int r = 0; r < 16; ++r) at4[r] = *(const f32x4*)(Atn + (size_t)r * H_DIM);

    const float* xb = x + c0 + lane * 4;
    const int ng = (p1 - p0 + 3) >> 2;

#define LDTOK(t_, g_) { _Pragma("unroll") for (int i_ = 0; i_ < 4; ++i_) { \
        int p_ = p0 + (g_) * 4 + i_; t_[i_] = order[seg + min(p_, cnt - 1)]; } }
#define LDX(xv_, t_) { _Pragma("unroll") for (int i_ = 0; i_ < 4; ++i_) \
        xv_[i_] = *(const f32x4*)(xb + (size_t)t_[i_] * H_DIM); }
#define PROC(xv_, pidx_) { \
        float a_[16]; \
        _Pragma("unroll") for (int r_ = 0; r_ < 16; ++r_) { \
            a_[r_] = xv_.x * at4[r_].x; \
            a_[r_] = fmaf(xv_.y, at4[r_].y, a_[r_]); \
            a_[r_] = fmaf(xv_.z, at4[r_].z, a_[r_]); \
            a_[r_] = fmaf(xv_.w, at4[r_].w, a_[r_]); \
            DPP_ADD(a_[r_], "quad_perm:[1,0,3,2]"); \
            DPP_ADD(a_[r_], "quad_perm:[2,3,0,1]"); \
            DPP_ADD(a_[r_], "row_ror:4"); \
            DPP_ADD(a_[r_], "row_ror:8"); \
            a_[r_] += __int_as_float( \
                __builtin_amdgcn_ds_swizzle(__float_as_int(a_[r_]), 0x401F)); \
        } \
        float o_ = a_[0]; \
        _Pragma("unroll") for (int r_ = 1; r_ < 16; ++r_) \
            o_ = (rsel == r_) ? a_[r_] : o_; \
        if (MODE == 0) { \
            if ((pidx_) < p1 && !(lane & 16)) \
                P[((size_t)piece * T_TOK + (seg + (pidx_))) * RANK + rsel] = o_; \
        } else { \
            o_ += __shfl_xor(o_, 32); \
            if ((pidx_) < p1 && lane < 16) \
                atomicAdd(&P[(size_t)(seg + (pidx_)) * RANK + rsel], o_); \
        } }

    int tA[4], tB[4];
    f32x4 xvA[4], xvB[4];
    LDTOK(tA, 0); LDX(xvA, tA);
    for (int g = 0; g < ng; g += 2) {
        const bool hasB = (g + 1 < ng);
        if (hasB) { LDTOK(tB, g + 1); LDX(xvB, tB); }
        {
            int pb = p0 + g * 4;
            PROC(xvA[0], pb + 0); PROC(xvA[1], pb + 1);
            PROC(xvA[2], pb + 2); PROC(xvA[3], pb + 3);
        }
        if (hasB) {
            if (g + 2 < ng) { LDTOK(tA, g + 2); LDX(xvA, tA); }
            int pb = p0 + (g + 1) * 4;
            PROC(xvB[0], pb + 0); PROC(xvB[1], pb + 1);
            PROC(xvB[2], pb + 2); PROC(xvB[3], pb + 3);
        }
    }
#undef LDTOK
#undef LDX
#undef PROC
}

// ---------------- reduce P[32][T][16] -> V[T][16] ----------------

__global__ void k_reducev(const float* __restrict__ P, float* __restrict__ V) {
    const int i = blockIdx.x * 256 + threadIdx.x;      // f32x4 index, < T*4
    const f32x4* Pb = (const f32x4*)P;
    f32x4 s0 = {0.f, 0.f, 0.f, 0.f}, s1 = s0, s2 = s0, s3 = s0;
#pragma unroll
    for (int c = 0; c < NPIECE; c += 4) {
        s0 += Pb[(size_t)(c + 0) * T_TOK * 4 + i];
        s1 += Pb[(size_t)(c + 1) * T_TOK * 4 + i];
        s2 += Pb[(size_t)(c + 2) * T_TOK * 4 + i];
        s3 += Pb[(size_t)(c + 3) * T_TOK * 4 + i];
    }
    ((f32x4*)V)[i] = (s0 + s1) + (s2 + s3);
}

// ---------------- expand: out[t] = result[t] + V[p] @ B[n] ----------------

__global__ __launch_bounds__(256, 2) void k_expand(
    const float* __restrict__ result, const float* __restrict__ lora_b,
    const float* __restrict__ V, const int* __restrict__ order,
    const int* __restrict__ counts, const int* __restrict__ offs,
    float* __restrict__ out) {
    const int n = blockIdx.z;
    const int cnt = counts[n];
    const int pbase = blockIdx.y * NPE;
    if (pbase >= cnt) return;
    const int seg = offs[n];
    const int o0 = blockIdx.x * 1024 + (threadIdx.x << 2);

    __shared__ float vlds[NPE * RANK];
    __shared__ int olds[NPE];
    const int np = min(NPE, cnt - pbase);

    if (threadIdx.x < np * 4)
        ((f32x4*)vlds)[threadIdx.x] =
            ((const f32x4*)V)[(size_t)(seg + pbase) * 4 + threadIdx.x];
    if (threadIdx.x < np) olds[threadIdx.x] = order[seg + pbase + threadIdx.x];

    f32x4 b[RANK];
    const float* Bn = lora_b + (size_t)n * RANK * O_DIM;
#pragma unroll
    for (int r = 0; r < RANK; r++)
        b[r] = *(const f32x4*)(Bn + (size_t)r * O_DIM + o0);

    __syncthreads();

    size_t offA = (size_t)olds[0] * O_DIM + o0;
    f32x4 rA = *(const f32x4*)(result + offA);
    size_t offB = 0;
    f32x4 rB = rA;
    if (np > 1) {
        offB = (size_t)olds[1] * O_DIM + o0;
        rB = *(const f32x4*)(result + offB);
    }

    for (int p = 0; p < np; ++p) {
        f32x4 rC = rB;
        size_t offC = 0;
        if (p + 2 < np) {
            offC = (size_t)olds[p + 2] * O_DIM + o0;
            rC = *(const f32x4*)(result + offC);
        }
        float va[RANK];
#pragma unroll
        for (int q = 0; q < 4; q++)
            *(f32x4*)&va[q * 4] = *(const f32x4*)&vlds[p * RANK + q * 4];
        f32x4 acc = rA;
#pragma unroll
        for (int r = 0; r < RANK; r++) {
            acc.x = fmaf(va[r], b[r].x, acc.x);
            acc.y = fmaf(va[r], b[r].y, acc.y);
            acc.z = fmaf(va[r], b[r].z, acc.z);
            acc.w = fmaf(va[r], b[r].w, acc.w);
        }
        __builtin_nontemporal_store(acc, (f32x4*)(out + offA));
        rA = rB; offA = offB;
        rB = rC; offB = offC;
    }
}

// ---------------- launch ----------------

extern "C" void kernel_launch(void* const* d_in, const int* in_sizes, int n_in,
                              void* d_out, int out_size, void* d_ws, size_t ws_size,
                              hipStream_t stream) {
    const float* result = (const float*)d_in[0];
    const float* x      = (const float*)d_in[1];
    const float* lora_a = (const float*)d_in[2];
    const float* lora_b = (const float*)d_in[3];
    const int*   aidx   = (const int*)d_in[4];
    float* out = (float*)d_out;

    const size_t vbytes  = (size_t)T_TOK * RANK * 4;             // 1 MB
    const size_t atbytes = (size_t)NA * RANK * H_DIM * 4;        // 2 MB
    const size_t pbytes  = (size_t)NPIECE * T_TOK * RANK * 4;    // 32 MB
    const size_t base_need = vbytes + (size_t)T_TOK * 4 + 3 * NA * 4 + atbytes;
    const bool big = ws_size >= base_need + pbytes;

    float* V    = (float*)d_ws;
    int* order  = (int*)((char*)d_ws + vbytes);
    int* counts = order + T_TOK;
    int* offs   = counts + NA;
    int* cursor = offs + NA;
    float* AT   = (float*)(cursor + NA);
    float* P    = (float*)((char*)d_ws + base_need);             // big path only

    k_zero<<<dim3(1), dim3(64), 0, stream>>>(counts);
    k_hist<<<dim3(64), dim3(256), 0, stream>>>(aidx, counts);
    k_prefix<<<dim3(1), dim3(64), 0, stream>>>(counts, offs, cursor);
    k_scatter<<<dim3(64), dim3(256), 0, stream>>>(aidx, cursor, order);
    k_transpose<<<dim3(16, NA), dim3(256), 0, stream>>>(lora_a, AT);

    if (big) {
        k_shrink<0><<<dim3(4, 32, NA), dim3(256), 0, stream>>>(x, AT, order, counts, offs, P);
        k_reducev<<<dim3(T_TOK * 4 / 256), dim3(256), 0, stream>>>(P, V);
    } else {
        k_zerov<<<dim3(T_TOK * 4 / 256), dim3(256), 0, stream>>>(V);
        k_shrink<1><<<dim3(4, 32, NA), dim3(256), 0, stream>>>(x, AT, order, counts, offs, V);
    }
    k_expand<<<dim3(4, 512, NA), dim3(256), 0, stream>>>(result, lora_b, V, order, counts, offs, out);
}

// Round 6
// 230.402 us; speedup vs baseline: 1.4944x; 1.1506x over previous
//
#include <hip/hip_runtime.h>

#define T_TOK 16384
#define H_DIM 4096
#define O_DIM 4096
#define NA 8
#define RANK 16
#define NKC 4              // K-chunks of 1024
#define NPE 32             // tokens per expand block

typedef float f32x4 __attribute__((ext_vector_type(4)));
typedef short bf16x8 __attribute__((ext_vector_type(8)));

// f32 -> bf16 (RTNE), bit-exact and cheap (3 VALU)
static __device__ __forceinline__ unsigned short f2bf(float f) {
    unsigned int u = __float_as_uint(f);
    u = (u + 0x7fffu + ((u >> 16) & 1u)) >> 16;
    return (unsigned short)u;
}

// ---------------- sort-by-adapter machinery ----------------

__global__ void k_zero(int* __restrict__ counts) {
    if (threadIdx.x < NA) counts[threadIdx.x] = 0;
}

__global__ void k_hist(const int* __restrict__ idx, int* __restrict__ counts) {
    __shared__ int h[NA];
    if (threadIdx.x < NA) h[threadIdx.x] = 0;
    __syncthreads();
    int t = blockIdx.x * blockDim.x + threadIdx.x;
    atomicAdd(&h[idx[t]], 1);
    __syncthreads();
    if (threadIdx.x < NA) atomicAdd(&counts[threadIdx.x], h[threadIdx.x]);
}

__global__ void k_prefix(const int* __restrict__ counts, int* __restrict__ offs,
                         int* __restrict__ cursor) {
    if (threadIdx.x == 0) {
        int run = 0;
        for (int n = 0; n < NA; n++) { offs[n] = run; cursor[n] = run; run += counts[n]; }
    }
}

__global__ void k_scatter(const int* __restrict__ idx, int* __restrict__ cursor,
                          int* __restrict__ order) {
    int t = blockIdx.x * blockDim.x + threadIdx.x;
    int a = idx[t];
    int lane = threadIdx.x & 63;
    for (int n = 0; n < NA; n++) {
        unsigned long long m = __ballot(a == n);
        if (m) {
            int leader = __ffsll((unsigned long long)m) - 1;
            int cnt = __popcll(m);
            int base = 0;
            if (lane == leader) base = atomicAdd(&cursor[n], cnt);
            base = __shfl(base, leader);
            if (a == n) {
                int rank = __popcll(m & ((1ull << lane) - 1ull));
                order[base + rank] = t;
            }
        }
    }
}

// ---------------- transpose A -> ATb[n][r][h] (bf16) ----------------
// grid (16, 8), block 256. LDS padded stride 17 -> conflict-free reads.

__global__ void k_transpose(const float* __restrict__ A, unsigned short* __restrict__ ATb) {
    const int n = blockIdx.y;
    const int h0 = blockIdx.x * 256;
    __shared__ float lds[256 * 17];
    const float4* src = (const float4*)(A + ((size_t)n * H_DIM + h0) * RANK);
#pragma unroll
    for (int k = 0; k < 4; ++k) {
        int f = k * 256 + threadIdx.x;
        float4 v = src[f];
        int row = (f * 4) >> 4, col = (f * 4) & 15;
        lds[row * 17 + col + 0] = v.x;
        lds[row * 17 + col + 1] = v.y;
        lds[row * 17 + col + 2] = v.z;
        lds[row * 17 + col + 3] = v.w;
    }
    __syncthreads();
    unsigned short* dst = ATb + (size_t)n * RANK * H_DIM;
#pragma unroll
    for (int r = 0; r < RANK; ++r)
        dst[(size_t)r * H_DIM + h0 + threadIdx.x] = f2bf(lds[threadIdx.x * 17 + r]);
}

// ---------------- shrink via MFMA: P[kc][t][r] partials ----------------
// grid (32, NKC, 8), block 256 = 4 waves. Wave owns one 16-token tile (grid-stride).
// mfma_f32_16x16x32_bf16: A-frag lane: m=lane&15, k=kg*8+j (kg=lane>>4, j=0..7)
//                         B-frag lane: n=lane&15, k=kg*8+j
//                         D:     lane: col=lane&15, row=kg*4+q
// A = x tile (loaded f32, converted in-reg), B = ATb (pre-converted bf16, L2-hot).

__global__ __launch_bounds__(256, 4) void k_shrink_mfma(
    const float* __restrict__ x, const unsigned short* __restrict__ atb,
    const int* __restrict__ order, const int* __restrict__ counts,
    const int* __restrict__ offs, float* __restrict__ P) {
    const int n = blockIdx.z;
    const int cnt = counts[n];
    if (cnt == 0) return;
    const int seg = offs[n];
    const int w = threadIdx.x >> 6, lane = threadIdx.x & 63;
    const int kc = blockIdx.y;
    const int mi = lane & 15, kg = lane >> 4;
    const int tiles = (cnt + 15) >> 4;

    const unsigned short* bp0 = atb + ((size_t)n * RANK + mi) * H_DIM + kc * 1024 + kg * 8;

    for (int tile = blockIdx.x * 4 + w; tile < tiles; tile += 128) {
        const int tbase = tile << 4;
        const int tok = order[seg + min(tbase + mi, cnt - 1)];
        const float* xp = x + (size_t)tok * H_DIM + kc * 1024 + kg * 8;

        f32x4 acc = {0.f, 0.f, 0.f, 0.f};
#pragma unroll 4
        for (int ks = 0; ks < 32; ++ks) {
            f32x4 xlo = *(const f32x4*)(xp + ks * 32);
            f32x4 xhi = *(const f32x4*)(xp + ks * 32 + 4);
            bf16x8 bfrag = *(const bf16x8*)(bp0 + ks * 32);
            bf16x8 afrag;
            afrag[0] = (short)f2bf(xlo.x); afrag[1] = (short)f2bf(xlo.y);
            afrag[2] = (short)f2bf(xlo.z); afrag[3] = (short)f2bf(xlo.w);
            afrag[4] = (short)f2bf(xhi.x); afrag[5] = (short)f2bf(xhi.y);
            afrag[6] = (short)f2bf(xhi.z); afrag[7] = (short)f2bf(xhi.w);
            acc = __builtin_amdgcn_mfma_f32_16x16x32_bf16(afrag, bfrag, acc, 0, 0, 0);
        }
#pragma unroll
        for (int q = 0; q < 4; ++q) {
            int pr = tbase + kg * 4 + q;
            if (pr < cnt)
                P[((size_t)kc * T_TOK + seg + pr) * RANK + mi] = acc[q];
        }
    }
}

// ---------------- expand: out[t] = result[t] + (sum_kc P[kc][t]) @ B[n] ----------------
// grid (4, 512, 8), block 256; B slice in regs; 2-deep NT prefetch on result; NT store.

__global__ __launch_bounds__(256, 3) void k_expand(
    const float* __restrict__ result, const float* __restrict__ lora_b,
    const float* __restrict__ P, const int* __restrict__ order,
    const int* __restrict__ counts, const int* __restrict__ offs,
    float* __restrict__ out) {
    const int n = blockIdx.z;
    const int cnt = counts[n];
    const int pbase = blockIdx.y * NPE;
    if (pbase >= cnt) return;
    const int seg = offs[n];
    const int o0 = blockIdx.x * 1024 + (threadIdx.x << 2);

    __shared__ float vlds[NPE * RANK];
    __shared__ int olds[NPE];
    const int np = min(NPE, cnt - pbase);

    if (threadIdx.x < np * 4) {
        const f32x4* Pb = (const f32x4*)P + (size_t)(seg + pbase) * 4 + threadIdx.x;
        f32x4 s = Pb[0];
#pragma unroll
        for (int c = 1; c < NKC; ++c) s += Pb[(size_t)c * T_TOK * 4];
        ((f32x4*)vlds)[threadIdx.x] = s;
    }
    if (threadIdx.x < np) olds[threadIdx.x] = order[seg + pbase + threadIdx.x];

    f32x4 b[RANK];
    const float* Bn = lora_b + (size_t)n * RANK * O_DIM;
#pragma unroll
    for (int r = 0; r < RANK; r++)
        b[r] = *(const f32x4*)(Bn + (size_t)r * O_DIM + o0);

    __syncthreads();

    size_t offA = (size_t)olds[0] * O_DIM + o0;
    f32x4 rA = __builtin_nontemporal_load((const f32x4*)(result + offA));
    size_t offB = 0;
    f32x4 rB = rA;
    if (np > 1) {
        offB = (size_t)olds[1] * O_DIM + o0;
        rB = __builtin_nontemporal_load((const f32x4*)(result + offB));
    }

    for (int p = 0; p < np; ++p) {
        f32x4 rC = rB;
        size_t offC = 0;
        if (p + 2 < np) {
            offC = (size_t)olds[p + 2] * O_DIM + o0;
            rC = __builtin_nontemporal_load((const f32x4*)(result + offC));
        }
        float va[RANK];
#pragma unroll
        for (int q = 0; q < 4; q++)
            *(f32x4*)&va[q * 4] = *(const f32x4*)&vlds[p * RANK + q * 4];
        f32x4 acc = rA;
#pragma unroll
        for (int r = 0; r < RANK; r++) {
            acc.x = fmaf(va[r], b[r].x, acc.x);
            acc.y = fmaf(va[r], b[r].y, acc.y);
            acc.z = fmaf(va[r], b[r].z, acc.z);
            acc.w = fmaf(va[r], b[r].w, acc.w);
        }
        __builtin_nontemporal_store(acc, (f32x4*)(out + offA));
        rA = rB; offA = offB;
        rB = rC; offB = offC;
    }
}

// ---------------- launch ----------------

extern "C" void kernel_launch(void* const* d_in, const int* in_sizes, int n_in,
                              void* d_out, int out_size, void* d_ws, size_t ws_size,
                              hipStream_t stream) {
    const float* result = (const float*)d_in[0];
    const float* x      = (const float*)d_in[1];
    const float* lora_a = (const float*)d_in[2];
    const float* lora_b = (const float*)d_in[3];
    const int*   aidx   = (const int*)d_in[4];
    float* out = (float*)d_out;

    const size_t pbytes  = (size_t)NKC * T_TOK * RANK * 4;       // 4 MB
    float* P    = (float*)d_ws;
    int* order  = (int*)((char*)d_ws + pbytes);
    int* counts = order + T_TOK;
    int* offs   = counts + NA;
    int* cursor = offs + NA;
    unsigned short* ATb = (unsigned short*)(cursor + NA);        // 1 MB

    k_zero<<<dim3(1), dim3(64), 0, stream>>>(counts);
    k_hist<<<dim3(64), dim3(256), 0, stream>>>(aidx, counts);
    k_prefix<<<dim3(1), dim3(64), 0, stream>>>(counts, offs, cursor);
    k_scatter<<<dim3(64), dim3(256), 0, stream>>>(aidx, cursor, order);
    k_transpose<<<dim3(16, NA), dim3(256), 0, stream>>>(lora_a, ATb);
    k_shrink_mfma<<<dim3(32, NKC, NA), dim3(256), 0, stream>>>(x, ATb, order, counts, offs, P);
    k_expand<<<dim3(4, 512, NA), dim3(256), 0, stream>>>(result, lora_b, P, order, counts, offs, out);
}

// Round 7
// 222.484 us; speedup vs baseline: 1.5476x; 1.0356x over previous
//
#include <hip/hip_runtime.h>

#define T_TOK 16384
#define H_DIM 4096
#define O_DIM 4096
#define NA 8
#define RANK 16

typedef float f32x4 __attribute__((ext_vector_type(4)));
typedef short bf16x8 __attribute__((ext_vector_type(8)));

// f32 -> bf16 (RTNE)
static __device__ __forceinline__ unsigned short f2bf(float f) {
    unsigned int u = __float_as_uint(f);
    u = (u + 0x7fffu + ((u >> 16) & 1u)) >> 16;
    return (unsigned short)u;
}

// ---------------- sort-by-adapter machinery ----------------

__global__ void k_zero(int* __restrict__ counts) {
    if (threadIdx.x < NA) counts[threadIdx.x] = 0;
}

__global__ void k_hist(const int* __restrict__ idx, int* __restrict__ counts) {
    __shared__ int h[NA];
    if (threadIdx.x < NA) h[threadIdx.x] = 0;
    __syncthreads();
    int t = blockIdx.x * blockDim.x + threadIdx.x;
    atomicAdd(&h[idx[t]], 1);
    __syncthreads();
    if (threadIdx.x < NA) atomicAdd(&counts[threadIdx.x], h[threadIdx.x]);
}

__global__ void k_prefix(const int* __restrict__ counts, int* __restrict__ offs,
                         int* __restrict__ cursor) {
    if (threadIdx.x == 0) {
        int run = 0;
        for (int n = 0; n < NA; n++) { offs[n] = run; cursor[n] = run; run += counts[n]; }
    }
}

__global__ void k_scatter(const int* __restrict__ idx, int* __restrict__ cursor,
                          int* __restrict__ order) {
    int t = blockIdx.x * blockDim.x + threadIdx.x;
    int a = idx[t];
    int lane = threadIdx.x & 63;
    for (int n = 0; n < NA; n++) {
        unsigned long long m = __ballot(a == n);
        if (m) {
            int leader = __ffsll((unsigned long long)m) - 1;
            int cnt = __popcll(m);
            int base = 0;
            if (lane == leader) base = atomicAdd(&cursor[n], cnt);
            base = __shfl(base, leader);
            if (a == n) {
                int rank = __popcll(m & ((1ull << lane) - 1ull));
                order[base + rank] = t;
            }
        }
    }
}

// ---------------- transpose A -> ATb[n][r][h] (bf16) ----------------

__global__ void k_transpose(const float* __restrict__ A, unsigned short* __restrict__ ATb) {
    const int n = blockIdx.y;
    const int h0 = blockIdx.x * 256;
    __shared__ float lds[256 * 17];
    const float4* src = (const float4*)(A + ((size_t)n * H_DIM + h0) * RANK);
#pragma unroll
    for (int k = 0; k < 4; ++k) {
        int f = k * 256 + threadIdx.x;
        float4 v = src[f];
        int row = (f * 4) >> 4, col = (f * 4) & 15;
        lds[row * 17 + col + 0] = v.x;
        lds[row * 17 + col + 1] = v.y;
        lds[row * 17 + col + 2] = v.z;
        lds[row * 17 + col + 3] = v.w;
    }
    __syncthreads();
    unsigned short* dst = ATb + (size_t)n * RANK * H_DIM;
#pragma unroll
    for (int r = 0; r < RANK; ++r)
        dst[(size_t)r * H_DIM + h0 + threadIdx.x] = f2bf(lds[threadIdx.x * 17 + r]);
}

// ---------------- fused: per 16-token tile, shrink (MFMA) then expand ----------------
// Block = 256 thr = 4 waves. Phase 1: wave w = K-quarter kc=w of the tile's
// [16 x 4096] @ [4096 x 16] shrink -> vp[w][16][16] in LDS; reduce to vsum.
// Phase 2: 4 col-quarters of 1024; per thread 4 cols; B slice in 64 VGPR (L2-hot);
// 2-deep NT prefetch on result rows; NT store to out. No global V/P traffic.

__global__ __launch_bounds__(256, 3) void k_fused(
    const float* __restrict__ result, const float* __restrict__ x,
    const unsigned short* __restrict__ atb, const float* __restrict__ lora_b,
    const int* __restrict__ order, const int* __restrict__ counts,
    const int* __restrict__ offs, float* __restrict__ out) {

    // block -> (adapter n, tile)
    const int bid = blockIdx.x;
    int n = 0, tile = 0, found = 0, acc_t = 0;
#pragma unroll
    for (int i = 0; i < NA; ++i) {
        int tn = (counts[i] + 15) >> 4;
        if (!found && bid < acc_t + tn) { n = i; tile = bid - acc_t; found = 1; }
        acc_t += tn;
    }
    if (!found) return;
    const int cnt = counts[n];
    const int seg = offs[n];
    const int tbase = tile << 4;
    const int np = min(16, cnt - tbase);

    __shared__ float vp[4][16][16];
    __shared__ float vsum[16][16];
    __shared__ int toks[16];

    const int w = threadIdx.x >> 6, lane = threadIdx.x & 63;
    const int mi = lane & 15, kg = lane >> 4;

    if (threadIdx.x < 16)
        toks[threadIdx.x] = order[seg + min(tbase + (int)threadIdx.x, cnt - 1)];

    // ---- phase 1: shrink quarter kc = w ----
    {
        const int tokm = order[seg + min(tbase + mi, cnt - 1)];
        const float* xp = x + (size_t)tokm * H_DIM + w * 1024 + kg * 8;
        const unsigned short* bp0 = atb + ((size_t)n * RANK + mi) * H_DIM + w * 1024 + kg * 8;

        f32x4 acc = {0.f, 0.f, 0.f, 0.f};
#pragma unroll 4
        for (int ks = 0; ks < 32; ++ks) {
            f32x4 xlo = *(const f32x4*)(xp + ks * 32);
            f32x4 xhi = *(const f32x4*)(xp + ks * 32 + 4);
            bf16x8 bfrag = *(const bf16x8*)(bp0 + ks * 32);
            bf16x8 afrag;
            afrag[0] = (short)f2bf(xlo.x); afrag[1] = (short)f2bf(xlo.y);
            afrag[2] = (short)f2bf(xlo.z); afrag[3] = (short)f2bf(xlo.w);
            afrag[4] = (short)f2bf(xhi.x); afrag[5] = (short)f2bf(xhi.y);
            afrag[6] = (short)f2bf(xhi.z); afrag[7] = (short)f2bf(xhi.w);
            acc = __builtin_amdgcn_mfma_f32_16x16x32_bf16(afrag, bfrag, acc, 0, 0, 0);
        }
#pragma unroll
        for (int q = 0; q < 4; ++q)
            vp[w][kg * 4 + q][mi] = acc[q];
    }
    __syncthreads();
    {
        const int p = threadIdx.x >> 4, r = threadIdx.x & 15;
        vsum[p][r] = (vp[0][p][r] + vp[1][p][r]) + (vp[2][p][r] + vp[3][p][r]);
    }
    __syncthreads();

    // ---- phase 2: expand 4 col-quarters ----
    const float* Bn = lora_b + (size_t)n * RANK * O_DIM;
#pragma unroll 1
    for (int q = 0; q < 4; ++q) {
        const int o0 = q * 1024 + (threadIdx.x << 2);
        f32x4 b[RANK];
#pragma unroll
        for (int r = 0; r < RANK; ++r)
            b[r] = *(const f32x4*)(Bn + (size_t)r * O_DIM + o0);

        size_t offA = (size_t)toks[0] * O_DIM + o0;
        f32x4 rA = __builtin_nontemporal_load((const f32x4*)(result + offA));
        size_t offB = 0;
        f32x4 rB = rA;
        if (np > 1) {
            offB = (size_t)toks[1] * O_DIM + o0;
            rB = __builtin_nontemporal_load((const f32x4*)(result + offB));
        }

        for (int p = 0; p < np; ++p) {
            f32x4 rC = rB;
            size_t offC = 0;
            if (p + 2 < np) {
                offC = (size_t)toks[p + 2] * O_DIM + o0;
                rC = __builtin_nontemporal_load((const f32x4*)(result + offC));
            }
            float va[RANK];
#pragma unroll
            for (int u = 0; u < 4; ++u)
                *(f32x4*)&va[u * 4] = *(const f32x4*)&vsum[p][u * 4];
            f32x4 acc = rA;
#pragma unroll
            for (int r = 0; r < RANK; ++r) {
                acc.x = fmaf(va[r], b[r].x, acc.x);
                acc.y = fmaf(va[r], b[r].y, acc.y);
                acc.z = fmaf(va[r], b[r].z, acc.z);
                acc.w = fmaf(va[r], b[r].w, acc.w);
            }
            __builtin_nontemporal_store(acc, (f32x4*)(out + offA));
            rA = rB; offA = offB;
            rB = rC; offB = offC;
        }
    }
}

// ---------------- launch ----------------

extern "C" void kernel_launch(void* const* d_in, const int* in_sizes, int n_in,
                              void* d_out, int out_size, void* d_ws, size_t ws_size,
                              hipStream_t stream) {
    const float* result = (const float*)d_in[0];
    const float* x      = (const float*)d_in[1];
    const float* lora_a = (const float*)d_in[2];
    const float* lora_b = (const float*)d_in[3];
    const int*   aidx   = (const int*)d_in[4];
    float* out = (float*)d_out;

    int* order  = (int*)d_ws;
    int* counts = order + T_TOK;
    int* offs   = counts + NA;
    int* cursor = offs + NA;
    unsigned short* ATb = (unsigned short*)(cursor + NA);        // 1 MB

    k_zero<<<dim3(1), dim3(64), 0, stream>>>(counts);
    k_hist<<<dim3(64), dim3(256), 0, stream>>>(aidx, counts);
    k_prefix<<<dim3(1), dim3(64), 0, stream>>>(counts, offs, cursor);
    k_scatter<<<dim3(64), dim3(256), 0, stream>>>(aidx, cursor, order);
    k_transpose<<<dim3(16, NA), dim3(256), 0, stream>>>(lora_a, ATb);
    k_fused<<<dim3(T_TOK / 16 + NA), dim3(256), 0, stream>>>(
        result, x, ATb, lora_b, order, counts, offs, out);
}